// Round 9
// baseline (246.327 us; speedup 1.0000x reference)
//
#include <hip/hip_runtime.h>
#include <math.h>

#define D 64
#define K 4096
// ONE-product fp16 scheme (field-tested R8, absmax 0.0): q~ = esq - 2*(zh.eh).
// Pair-diff sigma ~7.4e-3 -> MARGIN 0.08 = 10.8 sigma. All flips within
// margin land on the worklist -> exact fp32 resolve.
#define MARGIN 0.08f
#define KSPLIT 4
#define CPH (K / 16 / KSPLIT)  // chunks of 16 codes per half = 64
#define TS 8                   // chunks per LDS tile (16KB)
#define NT (CPH / TS)          // 8 tiles
#define TROWS 32               // rows per tail block (round-9: was 128)

typedef float f32x4 __attribute__((ext_vector_type(4)));
typedef _Float16 f16x8 __attribute__((ext_vector_type(8)));

// global -> LDS async DMA, 16B per lane (m97 pattern). LDS dst is
// wave-uniform base + lane*16; global src is per-lane.
#define GLOAD_LDS(g, l)                                              \
  __builtin_amdgcn_global_load_lds(                                  \
      (const __attribute__((address_space(1))) void*)(g),            \
      (__attribute__((address_space(3))) void*)(l), 16, 0, 0)

// ---------------------------------------------------------------------------
// Fused setup: zero counts+ctrl (re-poisoned every graph replay) + exact fp32
// esq + fp16 emb copy PRE-SWIZZLED into MFMA B-fragment order:
// element (code k=c*16+col, dim d=t*32+quad*8+j) -> ((c*2+t)*64+quad*16+col)*8+j
// ---------------------------------------------------------------------------
__global__ __launch_bounds__(256) void esplit_kernel(const float* __restrict__ emb,
                                                     short* __restrict__ e_h,
                                                     float* __restrict__ e_sq,
                                                     int* __restrict__ counts,
                                                     int* __restrict__ ctrl) {
  int i = blockIdx.x * 256 + threadIdx.x;  // [0, 32768)
  {
    int lane = i & 63;
    int t = (i >> 6) & 1;
    int c = i >> 7;
    int quad = lane >> 4, col = lane & 15;
    const float* src = emb + (size_t)(c * 16 + col) * D + t * 32 + quad * 8;
    f32x4 u0 = *(const f32x4*)src;
    f32x4 u1 = *(const f32x4*)(src + 4);
    f16x8 h;
#pragma unroll
    for (int j = 0; j < 8; ++j) {
      float x = (j < 4) ? u0[j] : u1[j - 4];
      h[j] = (_Float16)x;
    }
    *(f16x8*)(e_h + (size_t)i * 8) = h;
  }
  if (i < 128) ctrl[i] = 0;  // done counter + 64 loss slots
  if (i < K) {               // esq + counts duty for the first 16 blocks
    counts[i] = 0;
    const float* e = emb + (size_t)i * D;
    float s = 0.f;
#pragma unroll
    for (int d = 0; d < D; ++d) s = fmaf(e[d], e[d], s);
    e_sq[i] = s;
  }
}

// ---------------------------------------------------------------------------
// MFMA dist/argmin (field-tested R8): ONE-product fp16, 4 MFMA/chunk,
// LDS-staged B (32KB double-buffer, 1 barrier/8-chunk tile), seed/max-space
// tracking, explicit chunk-id, q-space conversion in epilogue.
// A[m=lane&15][k=quad*8+j]; B[n=lane&15][k=quad*8+j]; C/D row=quad*4+r, col=lane&15.
// ---------------------------------------------------------------------------
#define MFMA16(A, B, C) __builtin_amdgcn_mfma_f32_16x16x32_f16(A, B, C, 0, 0, 0)

__global__ __launch_bounds__(256, 2) void dist_kernel(const float* __restrict__ z_e,
                                                      const short* __restrict__ e_h,
                                                      const float* __restrict__ esq,
                                                      float* __restrict__ pbest,
                                                      float* __restrict__ psec,
                                                      int* __restrict__ pidx) {
  const int tid = threadIdx.x;
  const int wv = tid >> 6;
  const int lane = tid & 63;
  const int quad = lane >> 4, col = lane & 15;
  const int rowbase = blockIdx.x * 128 + wv * 32;
  const int half = blockIdx.y;
  const int c0 = half * CPH;

  __shared__ __align__(16) short sbuf[2 * TS * 1024];  // 2 x 16KB

  // ---- A fragments: 2 m-tiles x 2 k-halves, z -> RNE fp16 (one product) ----
  f16x8 a[2][2];
#pragma unroll
  for (int s = 0; s < 2; ++s) {
#pragma unroll
    for (int t = 0; t < 2; ++t) {
      const float* zr = z_e + (size_t)(rowbase + s * 16 + col) * D + t * 32 + quad * 8;
      f32x4 u0 = *(const f32x4*)zr;
      f32x4 u1 = *(const f32x4*)(zr + 4);
#pragma unroll
      for (int j = 0; j < 8; ++j) {
        float x = (j < 4) ? u0[j] : u1[j - 4];
        a[s][t][j] = (_Float16)x;
      }
    }
  }

  // Max-space tracking: acc = dot - esq/2; larger acc == smaller q = -2*acc.
  float best[8], second[8];
  int bidx[8];
#pragma unroll
  for (int i = 0; i < 8; ++i) {
    best[i] = -__builtin_inff();
    second[i] = -__builtin_inff();
    bidx[i] = 0;
  }

  const short* gB = e_h + (size_t)c0 * 1024;  // this half's B stream (shorts)
  const float* pE = esq + c0 * 16 + col;

  // ---- prologue: stage tile 0 into buffer 0 (wave wv stages its 4KB) ----
  {
    const short* src = gB + (size_t)wv * 2048 + (size_t)lane * 8;
    short* dst = sbuf + wv * 2048;  // wave-uniform LDS base
#pragma unroll
    for (int s = 0; s < 4; ++s) GLOAD_LDS(src + s * 512, dst + s * 512);
  }

  unsigned rbase = 0;  // read-buffer offset in shorts (0 or 8192)
  for (int t = 0; t < NT; ++t) {
    __syncthreads();  // drains vmcnt -> tile t's staged data is visible

    if (t + 1 < NT) {  // stage tile t+1 into the other buffer
      const short* src = gB + (size_t)(t + 1) * (TS * 1024) + wv * 2048 + lane * 8;
      short* dst = sbuf + (rbase ^ (TS * 1024)) + wv * 2048;
#pragma unroll
      for (int s = 0; s < 4; ++s) GLOAD_LDS(src + s * 512, dst + s * 512);
    }

    float eqt[TS];
#pragma unroll
    for (int j = 0; j < TS; ++j) eqt[j] = pE[(t * TS + j) * 16];

    const short* sB = sbuf + rbase;
#pragma unroll
    for (int j = 0; j < TS; ++j) {
      f16x8 b0 = *(const f16x8*)(sB + j * 1024 + lane * 8);
      f16x8 b1 = *(const f16x8*)(sB + j * 1024 + 512 + lane * 8);

      const float seed = -0.5f * eqt[j];
      f32x4 acc0 = {seed, seed, seed, seed};
      f32x4 acc1 = {seed, seed, seed, seed};
      acc0 = MFMA16(a[0][0], b0, acc0);
      acc1 = MFMA16(a[1][0], b0, acc1);
      acc0 = MFMA16(a[0][1], b1, acc0);
      acc1 = MFMA16(a[1][1], b1, acc1);

      const int cc = t * TS + j;
#pragma unroll
      for (int r = 0; r < 4; ++r) {
        float a0 = acc0[r];
        float ob = best[r];
        best[r] = fmaxf(ob, a0);
        second[r] = __builtin_amdgcn_fmed3f(ob, a0, second[r]);
        bidx[r] = (a0 > ob) ? cc : bidx[r];  // strict >: ties keep earlier chunk
      }
#pragma unroll
      for (int r = 0; r < 4; ++r) {
        float a1 = acc1[r];
        float ob = best[4 + r];
        best[4 + r] = fmaxf(ob, a1);
        second[4 + r] = __builtin_amdgcn_fmed3f(ob, a1, second[4 + r]);
        bidx[4 + r] = (a1 > ob) ? cc : bidx[4 + r];
      }
    }
    rbase ^= TS * 1024;
  }

  // ---- convert to q-space, merge across the 16 code-columns ----
#pragma unroll
  for (int i = 0; i < 8; ++i) {
    float b = -2.f * best[i];
    float s2 = -2.f * second[i];
    int ix = (c0 + bidx[i]) * 16 + col;
#pragma unroll
    for (int off = 1; off < 16; off <<= 1) {
      float ob = __shfl_xor(b, off);
      float os = __shfl_xor(s2, off);
      int oi = __shfl_xor(ix, off);
      float ns = fminf(fminf(s2, os), fmaxf(b, ob));
      if (ob < b || (ob == b && oi < ix)) ix = oi;
      b = fminf(b, ob);
      s2 = ns;
    }
    if (col == 0) {
      int row = rowbase + (i >> 2) * 16 + quad * 4 + (i & 3);
      size_t o = (size_t)half * 65536 + row;
      pbest[o] = b;
      psec[o] = s2;
      pidx[o] = ix;
    }
  }
}

// ---------------------------------------------------------------------------
// FUSED tail: merge + resolve + finalize + stats. Round-9: 2048 blocks x 32
// rows (was 512 x 128). R8 counters showed the tail latency-starved: occupancy
// 8.3%, VALU 3.3%, 85us for 5us of traffic — 512 blocks gave only 8 waves/CU
// peak against ~900cyc HBM latency chains. 4x finer grid -> ~24 waves/CU
// (VGPR 80, LDS 2.5KB allow 6 blocks/CU). Phases/math byte-identical.
// Sync budget stays O(blocks): 2048 done-atomics, 1 fence/block.
// ---------------------------------------------------------------------------
__global__ __launch_bounds__(256) void tail_kernel(const float* __restrict__ z_e,
                                                   const float* __restrict__ emb,
                                                   const float* __restrict__ esq,
                                                   const float* __restrict__ pbest,
                                                   const float* __restrict__ psec,
                                                   const int* __restrict__ pidx,
                                                   float* __restrict__ out_zq,
                                                   float* __restrict__ out_idx,
                                                   int* __restrict__ counts,
                                                   int* __restrict__ ctrl,
                                                   float* __restrict__ out_scalars,
                                                   int N) {
  const int tid = threadIdx.x;
  const int wave = tid >> 6;
  const int lane = tid & 63;
  const int base = blockIdx.x * TROWS;
  int* done = ctrl;
  float* loss_slots = (float*)(ctrl + 8);

  __shared__ int wl[TROWS];
  __shared__ int bidx_s[TROWS];
  __shared__ int wn;
  __shared__ int lastflag;
  __shared__ float zs[4][D];
  __shared__ float se[4];
  __shared__ int sa[4];

  if (tid == 0) wn = 0;
  __syncthreads();

  // ---- phase 1: per-row KSPLIT merge (field-tested math) ----
  if (tid < TROWS) {
    int row = base + tid;
    float b = pbest[row];
    float s2 = psec[row];
    int ix = pidx[row];
#pragma unroll
    for (int h = 1; h < KSPLIT; ++h) {
      size_t o = (size_t)h * 65536 + row;
      float bh = pbest[o];
      float sh = psec[o];
      int ih = pidx[o];
      s2 = fminf(fminf(s2, sh), fmaxf(b, bh));
      if (bh < b) ix = ih;  // strict <: ties keep lower-half (smaller) index
      b = fminf(b, bh);
    }
    bidx_s[tid] = ix;
    if (s2 - b < MARGIN) {
      int slot = atomicAdd(&wn, 1);  // LDS atomic
      wl[slot] = row;
    }
  }
  __syncthreads();

  // ---- phase 2: candidate-based exact resolve (field-tested core) ----
  const int n = wn;
  for (int j = wave; j < n; j += 4) {
    const int row = wl[j];
    if (lane < 16) ((f32x4*)zs[wave])[lane] = *((const f32x4*)(z_e + (size_t)row * D) + lane);

    float pb[KSPLIT], ps[KSPLIT];
    int pi[KSPLIT];
    float B = __builtin_inff();
#pragma unroll
    for (int h = 0; h < KSPLIT; ++h) {
      size_t o = (size_t)h * 65536 + row;
      pb[h] = pbest[o];
      ps[h] = psec[o];
      pi[h] = pidx[o];
      B = fminf(B, pb[h]);
    }
    const float lim = B + MARGIN;

    float bv = __builtin_inff();
    int bi = 0;
#pragma unroll
    for (int h = 0; h < KSPLIT; ++h) {
      if (ps[h] < lim) {
        // exact fp32 scan of this 1024-code half
        float hb = __builtin_inff();
        int hx = 0;
        for (int t = 0; t < 16; ++t) {
          int c = h * 1024 + t * 64 + lane;
          const f32x4* er = (const f32x4*)(emb + (size_t)c * D);
          f32x4 a = {0.f, 0.f, 0.f, 0.f};
#pragma unroll
          for (int i = 0; i < 16; ++i)
            a = __builtin_elementwise_fma(er[i], ((const f32x4*)zs[wave])[i], a);
          float dot = (a[0] + a[1]) + (a[2] + a[3]);
          float q = fmaf(-2.f, dot, esq[c]);
          if (q < hb) { hb = q; hx = c; }  // ascending t => first occurrence
        }
#pragma unroll
        for (int off = 32; off > 0; off >>= 1) {
          float ov = __shfl_down(hb, off);
          int oi = __shfl_down(hx, off);
          if (ov < hb || (ov == hb && oi < hx)) { hb = ov; hx = oi; }
        }
        hb = __shfl(hb, 0);
        hx = __shfl(hx, 0);
        if (hb < bv || (hb == bv && hx < bi)) { bv = hb; bi = hx; }
      } else if (pb[h] < lim) {
        // single candidate: exact dot for code pi[h]
        int c = pi[h];
        float p = emb[(size_t)c * D + lane] * zs[wave][lane];
#pragma unroll
        for (int off = 1; off < 64; off <<= 1) p += __shfl_xor(p, off);
        float q = fmaf(-2.f, p, esq[c]);
        if (q < bv || (q == bv && c < bi)) { bv = q; bi = c; }
      }
    }
    if (lane == 0) bidx_s[row - base] = bi;
  }
  __syncthreads();

  // ---- phase 3: finalize the block's 32 rows (2-row ILP per iteration) ----
  float lloss = 0.f;  // per-lane loss accumulator
  for (int r = wave; r < TROWS; r += 8) {
    const int r1 = r + 4;  // always < TROWS
    const int i0 = bidx_s[r];
    const int i1 = bidx_s[r1];
    const size_t row0 = base + r, row1 = base + r1;
    float ze0 = z_e[row0 * D + lane];
    float ze1 = z_e[row1 * D + lane];
    float zq0 = emb[(size_t)i0 * D + lane];
    float zq1 = emb[(size_t)i1 * D + lane];
    out_zq[row0 * D + lane] = ze0 + (zq0 - ze0);  // straight-through
    out_zq[row1 * D + lane] = ze1 + (zq1 - ze1);
    float d0 = zq0 - ze0, d1 = zq1 - ze1;
    lloss = fmaf(d0, d0, lloss);
    lloss = fmaf(d1, d1, lloss);
    if (lane == 0) {
      out_idx[row0] = (float)i0;
      out_idx[row1] = (float)i1;
      atomicAdd(&counts[i0], 1);
      atomicAdd(&counts[i1], 1);
    }
  }
#pragma unroll
  for (int off = 32; off > 0; off >>= 1) lloss += __shfl_down(lloss, off);
  if (lane == 0) atomicAdd(&loss_slots[blockIdx.x & 63], lloss);

  // ---- handshake: O(blocks) cost ----
  __syncthreads();  // all waves' global ops complete (waitcnt before barrier)
  if (tid == 0) {
    __threadfence();
    lastflag = (atomicAdd(done, 1) == (int)gridDim.x - 1);
  }
  __syncthreads();
  if (!lastflag) return;

  // ---- phase 4 (last block only): stats; cross-block reads via atomics ----
  float ent = 0.f;
  int act = 0;
  const float invN = 1.0f / (float)N;
  for (int k = tid; k < K; k += 256) {
    float p = (float)atomicAdd(&counts[k], 0) * invN;
    ent += p * logf(p + 1e-10f);
    act += (p > 0.001f) ? 1 : 0;
  }
#pragma unroll
  for (int off = 32; off > 0; off >>= 1) {
    ent += __shfl_down(ent, off);
    act += __shfl_down(act, off);
  }
  if (lane == 0) { se[wave] = ent; sa[wave] = act; }

  float L = 0.f;
  if (wave == 0) {
    L = atomicAdd(&loss_slots[lane], 0.f);  // 64 slots, one per lane
#pragma unroll
    for (int off = 32; off > 0; off >>= 1) L += __shfl_down(L, off);
  }
  __syncthreads();
  if (tid == 0) {
    float E = se[0] + se[1] + se[2] + se[3];
    int A = sa[0] + sa[1] + sa[2] + sa[3];
    out_scalars[0] = 0.25f * L / ((float)N * (float)D);  // commitment loss
    out_scalars[1] = expf(-E);                            // perplexity
    out_scalars[2] = (float)A;                            // n_active
  }
}

extern "C" void kernel_launch(void* const* d_in, const int* in_sizes, int n_in,
                              void* d_out, int out_size, void* d_ws, size_t ws_size,
                              hipStream_t stream) {
  const float* z_e = (const float*)d_in[0];
  const float* emb = (const float*)d_in[1];
  const int N = in_sizes[0] / D;  // 65536

  float* out = (float*)d_out;
  float* out_zq = out;
  float* out_idx = out + (size_t)N * D;
  float* out_scalars = out + (size_t)N * (D + 1);

  char* ws = (char*)d_ws;
  size_t o = 0;
  int* counts = (int*)(ws + o);      o += 16384;                  // 4096 ints
  int* ctrl = (int*)(ws + o);        o += 512;                    // done + 64 slots
  float* esq = (float*)(ws + o);     o += 16384;                  // 4096 f32
  short* e_h = (short*)(ws + o);     o += (size_t)K * D * 2;      // 512 KB (fp16)
  o += 8192;                                                      // pad
  float* pbest = (float*)(ws + o);   o += (size_t)KSPLIT * N * 4; // 1 MB
  float* psec = (float*)(ws + o);    o += (size_t)KSPLIT * N * 4; // 1 MB
  int* pidx = (int*)(ws + o);        o += (size_t)KSPLIT * N * 4; // 1 MB

  esplit_kernel<<<(K / 16) * 2 * 64 / 256, 256, 0, stream>>>(emb, e_h, esq,
                                                             counts, ctrl);
  dist_kernel<<<dim3(N / 128, KSPLIT), 256, 0, stream>>>(z_e, e_h, esq,
                                                         pbest, psec, pidx);
  tail_kernel<<<N / TROWS, 256, 0, stream>>>(z_e, emb, esq, pbest, psec, pidx,
                                             out_zq, out_idx, counts, ctrl,
                                             out_scalars, N);
}

// Round 10
// 206.847 us; speedup vs baseline: 1.1909x; 1.1909x over previous
//
#include <hip/hip_runtime.h>
#include <math.h>

#define D 64
#define K 4096
// ONE-product fp16 scheme (field-tested R8, absmax 0.0): q~ = esq - 2*(zh.eh).
// Pair-diff sigma ~7.4e-3 -> MARGIN 0.08 = 10.8 sigma. All flips within
// margin land on the worklist -> exact fp32 resolve.
#define MARGIN 0.08f
#define KSPLIT 4
#define CPH (K / 16 / KSPLIT)  // chunks of 16 codes per half = 64
#define TS 8                   // chunks per LDS tile (16KB)
#define NT (CPH / TS)          // 8 tiles
#define TROWS 128              // rows per tail block (R8 geometry: 512 blocks)

typedef float f32x4 __attribute__((ext_vector_type(4)));
typedef _Float16 f16x8 __attribute__((ext_vector_type(8)));

// global -> LDS async DMA, 16B per lane (m97 pattern). LDS dst is
// wave-uniform base + lane*16; global src is per-lane.
#define GLOAD_LDS(g, l)                                              \
  __builtin_amdgcn_global_load_lds(                                  \
      (const __attribute__((address_space(1))) void*)(g),            \
      (__attribute__((address_space(3))) void*)(l), 16, 0, 0)

// ---------------------------------------------------------------------------
// Fused setup: zero counts (re-poisoned every graph replay) + exact fp32
// esq + fp16 emb copy PRE-SWIZZLED into MFMA B-fragment order:
// element (code k=c*16+col, dim d=t*32+quad*8+j) -> ((c*2+t)*64+quad*16+col)*8+j
// ---------------------------------------------------------------------------
__global__ __launch_bounds__(256) void esplit_kernel(const float* __restrict__ emb,
                                                     short* __restrict__ e_h,
                                                     float* __restrict__ e_sq,
                                                     int* __restrict__ counts) {
  int i = blockIdx.x * 256 + threadIdx.x;  // [0, 32768)
  {
    int lane = i & 63;
    int t = (i >> 6) & 1;
    int c = i >> 7;
    int quad = lane >> 4, col = lane & 15;
    const float* src = emb + (size_t)(c * 16 + col) * D + t * 32 + quad * 8;
    f32x4 u0 = *(const f32x4*)src;
    f32x4 u1 = *(const f32x4*)(src + 4);
    f16x8 h;
#pragma unroll
    for (int j = 0; j < 8; ++j) {
      float x = (j < 4) ? u0[j] : u1[j - 4];
      h[j] = (_Float16)x;
    }
    *(f16x8*)(e_h + (size_t)i * 8) = h;
  }
  if (i < K) {  // esq + counts duty for the first 16 blocks
    counts[i] = 0;
    const float* e = emb + (size_t)i * D;
    float s = 0.f;
#pragma unroll
    for (int d = 0; d < D; ++d) s = fmaf(e[d], e[d], s);
    e_sq[i] = s;
  }
}

// ---------------------------------------------------------------------------
// MFMA dist/argmin (field-tested R8): ONE-product fp16, 4 MFMA/chunk,
// LDS-staged B (32KB double-buffer, 1 barrier/8-chunk tile), seed/max-space
// tracking, explicit chunk-id, q-space conversion in epilogue.
// A[m=lane&15][k=quad*8+j]; B[n=lane&15][k=quad*8+j]; C/D row=quad*4+r, col=lane&15.
// ---------------------------------------------------------------------------
#define MFMA16(A, B, C) __builtin_amdgcn_mfma_f32_16x16x32_f16(A, B, C, 0, 0, 0)

__global__ __launch_bounds__(256, 2) void dist_kernel(const float* __restrict__ z_e,
                                                      const short* __restrict__ e_h,
                                                      const float* __restrict__ esq,
                                                      float* __restrict__ pbest,
                                                      float* __restrict__ psec,
                                                      int* __restrict__ pidx) {
  const int tid = threadIdx.x;
  const int wv = tid >> 6;
  const int lane = tid & 63;
  const int quad = lane >> 4, col = lane & 15;
  const int rowbase = blockIdx.x * 128 + wv * 32;
  const int half = blockIdx.y;
  const int c0 = half * CPH;

  __shared__ __align__(16) short sbuf[2 * TS * 1024];  // 2 x 16KB

  // ---- A fragments: 2 m-tiles x 2 k-halves, z -> RNE fp16 (one product) ----
  f16x8 a[2][2];
#pragma unroll
  for (int s = 0; s < 2; ++s) {
#pragma unroll
    for (int t = 0; t < 2; ++t) {
      const float* zr = z_e + (size_t)(rowbase + s * 16 + col) * D + t * 32 + quad * 8;
      f32x4 u0 = *(const f32x4*)zr;
      f32x4 u1 = *(const f32x4*)(zr + 4);
#pragma unroll
      for (int j = 0; j < 8; ++j) {
        float x = (j < 4) ? u0[j] : u1[j - 4];
        a[s][t][j] = (_Float16)x;
      }
    }
  }

  // Max-space tracking: acc = dot - esq/2; larger acc == smaller q = -2*acc.
  float best[8], second[8];
  int bidx[8];
#pragma unroll
  for (int i = 0; i < 8; ++i) {
    best[i] = -__builtin_inff();
    second[i] = -__builtin_inff();
    bidx[i] = 0;
  }

  const short* gB = e_h + (size_t)c0 * 1024;  // this half's B stream (shorts)
  const float* pE = esq + c0 * 16 + col;

  // ---- prologue: stage tile 0 into buffer 0 (wave wv stages its 4KB) ----
  {
    const short* src = gB + (size_t)wv * 2048 + (size_t)lane * 8;
    short* dst = sbuf + wv * 2048;  // wave-uniform LDS base
#pragma unroll
    for (int s = 0; s < 4; ++s) GLOAD_LDS(src + s * 512, dst + s * 512);
  }

  unsigned rbase = 0;  // read-buffer offset in shorts (0 or 8192)
  for (int t = 0; t < NT; ++t) {
    __syncthreads();  // drains vmcnt -> tile t's staged data is visible

    if (t + 1 < NT) {  // stage tile t+1 into the other buffer
      const short* src = gB + (size_t)(t + 1) * (TS * 1024) + wv * 2048 + lane * 8;
      short* dst = sbuf + (rbase ^ (TS * 1024)) + wv * 2048;
#pragma unroll
      for (int s = 0; s < 4; ++s) GLOAD_LDS(src + s * 512, dst + s * 512);
    }

    float eqt[TS];
#pragma unroll
    for (int j = 0; j < TS; ++j) eqt[j] = pE[(t * TS + j) * 16];

    const short* sB = sbuf + rbase;
#pragma unroll
    for (int j = 0; j < TS; ++j) {
      f16x8 b0 = *(const f16x8*)(sB + j * 1024 + lane * 8);
      f16x8 b1 = *(const f16x8*)(sB + j * 1024 + 512 + lane * 8);

      const float seed = -0.5f * eqt[j];
      f32x4 acc0 = {seed, seed, seed, seed};
      f32x4 acc1 = {seed, seed, seed, seed};
      acc0 = MFMA16(a[0][0], b0, acc0);
      acc1 = MFMA16(a[1][0], b0, acc1);
      acc0 = MFMA16(a[0][1], b1, acc0);
      acc1 = MFMA16(a[1][1], b1, acc1);

      const int cc = t * TS + j;
#pragma unroll
      for (int r = 0; r < 4; ++r) {
        float a0 = acc0[r];
        float ob = best[r];
        best[r] = fmaxf(ob, a0);
        second[r] = __builtin_amdgcn_fmed3f(ob, a0, second[r]);
        bidx[r] = (a0 > ob) ? cc : bidx[r];  // strict >: ties keep earlier chunk
      }
#pragma unroll
      for (int r = 0; r < 4; ++r) {
        float a1 = acc1[r];
        float ob = best[4 + r];
        best[4 + r] = fmaxf(ob, a1);
        second[4 + r] = __builtin_amdgcn_fmed3f(ob, a1, second[4 + r]);
        bidx[4 + r] = (a1 > ob) ? cc : bidx[4 + r];
      }
    }
    rbase ^= TS * 1024;
  }

  // ---- convert to q-space, merge across the 16 code-columns ----
#pragma unroll
  for (int i = 0; i < 8; ++i) {
    float b = -2.f * best[i];
    float s2 = -2.f * second[i];
    int ix = (c0 + bidx[i]) * 16 + col;
#pragma unroll
    for (int off = 1; off < 16; off <<= 1) {
      float ob = __shfl_xor(b, off);
      float os = __shfl_xor(s2, off);
      int oi = __shfl_xor(ix, off);
      float ns = fminf(fminf(s2, os), fmaxf(b, ob));
      if (ob < b || (ob == b && oi < ix)) ix = oi;
      b = fminf(b, ob);
      s2 = ns;
    }
    if (col == 0) {
      int row = rowbase + (i >> 2) * 16 + quad * 4 + (i & 3);
      size_t o = (size_t)half * 65536 + row;
      pbest[o] = b;
      psec[o] = s2;
      pidx[o] = ix;
    }
  }
}

// ---------------------------------------------------------------------------
// FUSED tail: merge + resolve + finalize. Round-10: the last-block stats
// handshake is DELETED — R9 proved same-address device atomics cost
// ~150cyc each serialized (512->2048 blocks: tail 85->117us). Per-block
// loss now goes to block_loss[blockIdx] by PLAIN STORE (zero contention);
// stats moves back to its own tiny kernel. Geometry = R8's measured-best
// 512 blocks x 128 rows. Phase math all field-tested.
// ---------------------------------------------------------------------------
__global__ __launch_bounds__(256) void tail_kernel(const float* __restrict__ z_e,
                                                   const float* __restrict__ emb,
                                                   const float* __restrict__ esq,
                                                   const float* __restrict__ pbest,
                                                   const float* __restrict__ psec,
                                                   const int* __restrict__ pidx,
                                                   float* __restrict__ out_zq,
                                                   float* __restrict__ out_idx,
                                                   int* __restrict__ counts,
                                                   float* __restrict__ block_loss) {
  const int tid = threadIdx.x;
  const int wave = tid >> 6;
  const int lane = tid & 63;
  const int base = blockIdx.x * TROWS;

  __shared__ int wl[TROWS];
  __shared__ int bidx_s[TROWS];
  __shared__ int wn;
  __shared__ float zs[4][D];
  __shared__ float ls[4];

  if (tid == 0) wn = 0;
  __syncthreads();

  // ---- phase 1: per-row KSPLIT merge (field-tested math) ----
  if (tid < TROWS) {
    int row = base + tid;
    float b = pbest[row];
    float s2 = psec[row];
    int ix = pidx[row];
#pragma unroll
    for (int h = 1; h < KSPLIT; ++h) {
      size_t o = (size_t)h * 65536 + row;
      float bh = pbest[o];
      float sh = psec[o];
      int ih = pidx[o];
      s2 = fminf(fminf(s2, sh), fmaxf(b, bh));
      if (bh < b) ix = ih;  // strict <: ties keep lower-half (smaller) index
      b = fminf(b, bh);
    }
    bidx_s[tid] = ix;
    if (s2 - b < MARGIN) {
      int slot = atomicAdd(&wn, 1);  // LDS atomic
      wl[slot] = row;
    }
  }
  __syncthreads();

  // ---- phase 2: candidate-based exact resolve (field-tested core) ----
  const int n = wn;
  for (int j = wave; j < n; j += 4) {
    const int row = wl[j];
    if (lane < 16) ((f32x4*)zs[wave])[lane] = *((const f32x4*)(z_e + (size_t)row * D) + lane);

    float pb[KSPLIT], ps[KSPLIT];
    int pi[KSPLIT];
    float B = __builtin_inff();
#pragma unroll
    for (int h = 0; h < KSPLIT; ++h) {
      size_t o = (size_t)h * 65536 + row;
      pb[h] = pbest[o];
      ps[h] = psec[o];
      pi[h] = pidx[o];
      B = fminf(B, pb[h]);
    }
    const float lim = B + MARGIN;

    float bv = __builtin_inff();
    int bi = 0;
#pragma unroll
    for (int h = 0; h < KSPLIT; ++h) {
      if (ps[h] < lim) {
        // exact fp32 scan of this 1024-code half
        float hb = __builtin_inff();
        int hx = 0;
        for (int t = 0; t < 16; ++t) {
          int c = h * 1024 + t * 64 + lane;
          const f32x4* er = (const f32x4*)(emb + (size_t)c * D);
          f32x4 a = {0.f, 0.f, 0.f, 0.f};
#pragma unroll
          for (int i = 0; i < 16; ++i)
            a = __builtin_elementwise_fma(er[i], ((const f32x4*)zs[wave])[i], a);
          float dot = (a[0] + a[1]) + (a[2] + a[3]);
          float q = fmaf(-2.f, dot, esq[c]);
          if (q < hb) { hb = q; hx = c; }  // ascending t => first occurrence
        }
#pragma unroll
        for (int off = 32; off > 0; off >>= 1) {
          float ov = __shfl_down(hb, off);
          int oi = __shfl_down(hx, off);
          if (ov < hb || (ov == hb && oi < hx)) { hb = ov; hx = oi; }
        }
        hb = __shfl(hb, 0);
        hx = __shfl(hx, 0);
        if (hb < bv || (hb == bv && hx < bi)) { bv = hb; bi = hx; }
      } else if (pb[h] < lim) {
        // single candidate: exact dot for code pi[h]
        int c = pi[h];
        float p = emb[(size_t)c * D + lane] * zs[wave][lane];
#pragma unroll
        for (int off = 1; off < 64; off <<= 1) p += __shfl_xor(p, off);
        float q = fmaf(-2.f, p, esq[c]);
        if (q < bv || (q == bv && c < bi)) { bv = q; bi = c; }
      }
    }
    if (lane == 0) bidx_s[row - base] = bi;
  }
  __syncthreads();

  // ---- phase 3: finalize the block's 128 rows (2-row ILP per iteration) ----
  float lloss = 0.f;  // per-lane loss accumulator
  for (int r = wave; r < TROWS; r += 8) {
    const int r1 = r + 4;  // always < TROWS
    const int i0 = bidx_s[r];
    const int i1 = bidx_s[r1];
    const size_t row0 = base + r, row1 = base + r1;
    float ze0 = z_e[row0 * D + lane];
    float ze1 = z_e[row1 * D + lane];
    float zq0 = emb[(size_t)i0 * D + lane];
    float zq1 = emb[(size_t)i1 * D + lane];
    out_zq[row0 * D + lane] = ze0 + (zq0 - ze0);  // straight-through
    out_zq[row1 * D + lane] = ze1 + (zq1 - ze1);
    float d0 = zq0 - ze0, d1 = zq1 - ze1;
    lloss = fmaf(d0, d0, lloss);
    lloss = fmaf(d1, d1, lloss);
    if (lane == 0) {
      out_idx[row0] = (float)i0;
      out_idx[row1] = (float)i1;
      atomicAdd(&counts[i0], 1);
      atomicAdd(&counts[i1], 1);
    }
  }
#pragma unroll
  for (int off = 32; off > 0; off >>= 1) lloss += __shfl_down(lloss, off);
  if (lane == 0) ls[wave] = lloss;
  __syncthreads();
  if (tid == 0) block_loss[blockIdx.x] = ls[0] + ls[1] + ls[2] + ls[3];
}

// ---------------------------------------------------------------------------
// Final scalars: commitment loss, perplexity, n_active. Single block.
// (Field-tested R0-R5. Kernel boundary orders the tail's atomics/stores.)
// ---------------------------------------------------------------------------
__global__ __launch_bounds__(1024) void stats_kernel(const float* __restrict__ block_loss,
                                                     int nblocks,
                                                     const int* __restrict__ counts,
                                                     float* __restrict__ out_scalars,
                                                     int N) {
  const int tid = threadIdx.x;
  const int wave = tid >> 6;
  const int lane = tid & 63;

  float lsum = 0.f;
  for (int i = tid; i < nblocks; i += 1024) lsum += block_loss[i];

  float ent = 0.f;
  int act = 0;
  const float invN = 1.0f / (float)N;
  for (int k = tid; k < K; k += 1024) {
    float p = (float)counts[k] * invN;
    ent += p * logf(p + 1e-10f);
    act += (p > 0.001f) ? 1 : 0;
  }

#pragma unroll
  for (int off = 32; off > 0; off >>= 1) {
    lsum += __shfl_down(lsum, off);
    ent += __shfl_down(ent, off);
    act += __shfl_down(act, off);
  }

  __shared__ float sl[16], se[16];
  __shared__ int sa[16];
  if (lane == 0) { sl[wave] = lsum; se[wave] = ent; sa[wave] = act; }
  __syncthreads();
  if (tid == 0) {
    float L = 0.f, E = 0.f;
    int A = 0;
#pragma unroll
    for (int w = 0; w < 16; ++w) { L += sl[w]; E += se[w]; A += sa[w]; }
    out_scalars[0] = 0.25f * L / ((float)N * (float)D);  // commitment loss
    out_scalars[1] = expf(-E);                            // perplexity
    out_scalars[2] = (float)A;                            // n_active
  }
}

extern "C" void kernel_launch(void* const* d_in, const int* in_sizes, int n_in,
                              void* d_out, int out_size, void* d_ws, size_t ws_size,
                              hipStream_t stream) {
  const float* z_e = (const float*)d_in[0];
  const float* emb = (const float*)d_in[1];
  const int N = in_sizes[0] / D;  // 65536

  float* out = (float*)d_out;
  float* out_zq = out;
  float* out_idx = out + (size_t)N * D;
  float* out_scalars = out + (size_t)N * (D + 1);

  char* ws = (char*)d_ws;
  size_t o = 0;
  int* counts = (int*)(ws + o);      o += 16384;                  // 4096 ints
  float* block_loss = (float*)(ws + o); o += 4096;                // 512+ f32
  float* esq = (float*)(ws + o);     o += 16384;                  // 4096 f32
  short* e_h = (short*)(ws + o);     o += (size_t)K * D * 2;      // 512 KB (fp16)
  o += 8192;                                                      // pad
  float* pbest = (float*)(ws + o);   o += (size_t)KSPLIT * N * 4; // 1 MB
  float* psec = (float*)(ws + o);    o += (size_t)KSPLIT * N * 4; // 1 MB
  int* pidx = (int*)(ws + o);        o += (size_t)KSPLIT * N * 4; // 1 MB

  esplit_kernel<<<(K / 16) * 2 * 64 / 256, 256, 0, stream>>>(emb, e_h, esq, counts);
  dist_kernel<<<dim3(N / 128, KSPLIT), 256, 0, stream>>>(z_e, e_h, esq,
                                                         pbest, psec, pidx);
  tail_kernel<<<N / TROWS, 256, 0, stream>>>(z_e, emb, esq, pbest, psec, pidx,
                                             out_zq, out_idx, counts, block_loss);
  stats_kernel<<<1, 1024, 0, stream>>>(block_loss, N / TROWS, counts,
                                       out_scalars, N);
}